// Round 6
// baseline (2102.838 us; speedup 1.0000x reference)
//
#include <hip/hip_runtime.h>
#include <cstddef>
#include <cstdint>

typedef unsigned short ushort_t;
typedef __attribute__((ext_vector_type(8))) short bf16x8;
typedef __attribute__((ext_vector_type(4))) float f32x4;

#define Bb 256
#define Hh 1024
#define Ff 512
#define Tt 128

// ---------- helpers ----------
__device__ __forceinline__ ushort_t f2bf(float f) {
    unsigned int u = __float_as_uint(f);
    unsigned int r = (u + 0x7FFFu + ((u >> 16) & 1u)) >> 16;
    return (ushort_t)r;
}
__device__ __forceinline__ float sigf(float x)  { return 1.0f / (1.0f + __expf(-x)); }
__device__ __forceinline__ float tanhf_(float x){ return 2.0f / (1.0f + __expf(-2.0f * x)) - 1.0f; }

// ---------- weight swizzle: row-major fp32 [K][N] -> bf16 B-fragment blocks ----------
// 1KB blocks [ntile][kstep]; within: lane=(koff/8)*16+(n%16), j=koff%8.
// modes 0/1: gate-interleaved ntile = ugroup*4 + gate. mode 2 (Wd): plain.
__global__ void swz(const float* __restrict__ s0, const float* __restrict__ s1,
                    ushort_t* __restrict__ dst, int K, int N, int mode, int total)
{
    int KB = K >> 5;
    for (int idx = blockIdx.x * blockDim.x + threadIdx.x; idx < total;
         idx += gridDim.x * blockDim.x) {
        int blk   = idx >> 9;
        int lane  = (idx >> 3) & 63;
        int j     = idx & 7;
        int ntile = blk / KB;
        int kstep = blk - ntile * KB;
        int k = (kstep << 5) + ((lane >> 4) << 3) + j;
        int n;
        if (mode == 2) n = (ntile << 4) + (lane & 15);
        else           n = ((ntile & 3) << 10) + ((ntile >> 2) << 4) + (lane & 15);
        float v;
        if (mode == 0)      v = s0[(size_t)k * N + n] + s1[(size_t)k * N + n];
        else if (mode == 1) v = (k < 1024) ? s0[(size_t)k * N + n]
                                           : s1[(size_t)(k - 1024) * N + n];
        else                v = s0[(size_t)k * N + n];
        dst[idx] = f2bf(v);
    }
}

// ---------- A0 = [x0 | h0] as bf16, row-major [256][2048] ----------
__global__ void mk_a0(const float* __restrict__ x0, const float* __restrict__ h0,
                      ushort_t* __restrict__ a0)
{
    int idx = blockIdx.x * blockDim.x + threadIdx.x;
    if (idx >= Bb * 2048) return;
    int r = idx >> 11, k = idx & 2047;
    float v = (k < 1024) ? x0[r * 1024 + k] : h0[r * 1024 + k - 1024];
    a0[idx] = f2bf(v);
}

__global__ void zero_bar(int* bar) {
    int i = blockIdx.x * blockDim.x + threadIdx.x;
    if (i < 8704) bar[i] = 0;
}

// barrier word layout in bar[] (ints; 128B-spaced lines):
//   xcd arrival x : bar[x*32]          (x=0..7, physical XCD, +32/step)
//   gflag g       : bar[256 + g*32]    (g=0..7, +8/step; ONE poller: master g)
//   bflag id      : bar[512 + id*32]   (id=0..255, +1/step; ONE poller: block id)
#define BAR_GFLAG 256
#define BAR_BFLAG 512

// ---------- step 0 (K=2048, Mcat streamed): round-2 kernel, proven ----------
__global__ __launch_bounds__(256) void lstm_step(
    const ushort_t* __restrict__ Ap, int K,
    const ushort_t* __restrict__ Bw,
    const float* cin, float* cout,
    ushort_t* __restrict__ seqt,
    const float* __restrict__ bias)
{
    __shared__ __align__(16) ushort_t lA[32 * 512];
    __shared__ __align__(16) ushort_t lB[32 * 512];

    const int tid = threadIdx.x, w = tid >> 6, lane = tid & 63;
    const int id = blockIdx.x;
    const int ntg = ((id & 7) << 3) | (id >> 5);
    const int bt  = (id >> 3) & 3;
    const int r0 = bt << 6, hb = ntg << 4;
    const int wr = w >> 1, wc = w & 1;
    const int KB = K >> 5;

    f32x4 acc[2][2];
    #pragma unroll
    for (int m = 0; m < 2; ++m)
        #pragma unroll
        for (int n = 0; n < 2; ++n) acc[m][n] = (f32x4){0.f, 0.f, 0.f, 0.f};

    const int kp = tid & 31;
    const int q_a = kp & 3, kk_a = kp >> 2;

    for (int kc = 0; kc < K; kc += 256) {
        bf16x8 va[8];
        #pragma unroll
        for (int i = 0; i < 8; ++i) {
            int row = (i << 3) + (tid >> 5);
            va[i] = *(const bf16x8*)(Ap + (size_t)(r0 + row) * K + kc + (kp << 3));
        }
        bf16x8 vb[8];
        #pragma unroll
        for (int i = 0; i < 8; ++i)
            vb[i] = *(const bf16x8*)(Bw +
                ((((size_t)((ntg << 2) + w)) * KB + (kc >> 5) + i) << 9) + (lane << 3));
        #pragma unroll
        for (int i = 0; i < 8; ++i) {
            int row = (i << 3) + (tid >> 5);
            int msub = row >> 4, mm = row & 15;
            int pos = (q_a << 4) | (mm ^ (((kk_a << 2) + q_a) & 15));
            *(bf16x8*)&lA[((((kk_a << 2) + msub) << 6) + pos) << 3] = va[i];
        }
        #pragma unroll
        for (int i = 0; i < 8; ++i)
            *(bf16x8*)&lB[(((i << 2) + w) << 9) + (lane << 3)] = vb[i];
        __syncthreads();

        #pragma unroll
        for (int kk = 0; kk < 8; ++kk) {
            const int qq = lane >> 4, mm = lane & 15;
            const int pos = (qq << 4) | (mm ^ (((kk << 2) + qq) & 15));
            bf16x8 af[2], bfr[2];
            #pragma unroll
            for (int m = 0; m < 2; ++m)
                af[m] = *(const bf16x8*)&lA[((((kk << 2) + (wr << 1) + m) << 6) + pos) << 3];
            #pragma unroll
            for (int n = 0; n < 2; ++n)
                bfr[n] = *(const bf16x8*)&lB[((((kk << 2) + (wc << 1) + n) << 6) + lane) << 3];
            #pragma unroll
            for (int m = 0; m < 2; ++m)
                #pragma unroll
                for (int n = 0; n < 2; ++n)
                    acc[m][n] = __builtin_amdgcn_mfma_f32_16x16x32_bf16(
                        af[m], bfr[n], acc[m][n], 0, 0, 0);
        }
        __syncthreads();
    }

    float* lZ = (float*)lA;
    {
        int q = lane >> 4, nl = lane & 15;
        #pragma unroll
        for (int m = 0; m < 2; ++m)
            #pragma unroll
            for (int n = 0; n < 2; ++n)
                #pragma unroll
                for (int r = 0; r < 4; ++r)
                    lZ[((wr << 5) + (m << 4) + (q << 2) + r) * 68 +
                       (wc << 5) + (n << 4) + nl] = acc[m][n][r];
    }
    __syncthreads();

    #pragma unroll
    for (int i = 0; i < 4; ++i) {
        int idx = (i << 8) + tid;
        int row = idx >> 4, u = idx & 15;
        float zi = lZ[row * 68 +      u] + bias[       hb + u];
        float zf = lZ[row * 68 + 16 + u] + bias[1024 + hb + u];
        float zg = lZ[row * 68 + 32 + u] + bias[2048 + hb + u];
        float zo = lZ[row * 68 + 48 + u] + bias[3072 + hb + u];
        size_t cidx = (size_t)(r0 + row) * Hh + hb + u;
        float cp = cin[cidx];
        float cn = sigf(zf) * cp + sigf(zi) * tanhf_(zg);
        cout[cidx] = cn;
        seqt[cidx] = f2bf(sigf(zo) * tanhf_(cn));
    }
}

// ---------- persistent scan, steps 1..127 ----------
// 256 blocks (1/CU), 256 threads, __launch_bounds__(256,1) -> full VGPR budget.
// B (128 KB) LDS-resident; A loaded global->register directly in MFMA fragment
// layout (8-deep prefetch window) -> K-loop has ZERO __syncthreads and no A
// LDS traffic. h-stores nontemporal (minimize XCD-last wbl2 dirty walk).
// Barrier v4: relaxed arrival on physical-XCD counter; XCD-last: 1 RELEASE
// (wbl2) + 8 relaxed gflag adds; masters (id<8) poll own gflag (1 poller/line)
// then broadcast 32 fire-and-forget adds to per-block lines; each block polls
// its private line. Zero RMW contention (round-5 residual suspect).
__global__ __launch_bounds__(256, 1) void lstm_scan(
    ushort_t* __restrict__ seq,
    const ushort_t* __restrict__ Msum,
    const float* __restrict__ bias,
    const float* __restrict__ cin,
    int* __restrict__ bar)
{
    __shared__ __align__(16) ushort_t lB[65536];   // 128 KB resident B
    __shared__ float lZ[64 * 68];                  // 17.4 KB Z exchange

    const int tid = threadIdx.x, w = tid >> 6, lane = tid & 63;
    const int id = blockIdx.x;
    const int ntg = ((id & 7) << 3) | (id >> 5);
    const int bt  = (id >> 3) & 3;
    const int r0 = bt << 6, hb = ntg << 4;
    const int wr = w >> 1, wc = w & 1;

    // resident B: contiguous 128 KB slice (ntile-major global layout)
    {
        const ushort_t* src = Msum + ((size_t)ntg << 16);
        #pragma unroll
        for (int i = 0; i < 32; ++i)
            *(bf16x8*)&lB[((i << 8) + tid) << 3] =
                *(const bf16x8*)(src + (((i << 8) + tid) << 3));
    }

    // c-state + bias in registers (thread->cell map static across steps)
    float c_reg[4], bi[4], bfv[4], bg[4], bo[4];
    #pragma unroll
    for (int i = 0; i < 4; ++i) {
        int idx = (i << 8) + tid;
        int row = idx >> 4, u = idx & 15;
        c_reg[i] = cin[(size_t)(r0 + row) * Hh + hb + u];
        bi[i]  = bias[       hb + u];
        bfv[i] = bias[1024 + hb + u];
        bg[i]  = bias[2048 + hb + u];
        bo[i]  = bias[3072 + hb + u];
    }

    // A-fragment geometry (16x16x32 A-layout: row=lane&15, k=(lane>>4)*8+j):
    // wave (wr,*) rows: r0 + wr*32 + m*16 + (lane&15); both wc waves load same A.
    const int arow0 = r0 + (wr << 5) + (lane & 15);
    const int kcol  = (lane >> 4) << 3;

    for (int t = 1; t < Tt; ++t) {
        const ushort_t* a0p = seq + ((size_t)(t - 1) << 18) + (size_t)arow0 * Hh + kcol;
        const ushort_t* a1p = a0p + 16 * Hh;   // m=1 rows

        f32x4 acc[2][2];
        #pragma unroll
        for (int m = 0; m < 2; ++m)
            #pragma unroll
            for (int n = 0; n < 2; ++n) acc[m][n] = (f32x4){0.f, 0.f, 0.f, 0.f};

        bf16x8 aw[8][2];   // 8-deep prefetch window (64 VGPR)
        #pragma unroll
        for (int p = 0; p < 8; ++p) {
            aw[p][0] = *(const bf16x8*)(a0p + (p << 5));
            aw[p][1] = *(const bf16x8*)(a1p + (p << 5));
        }
        #pragma unroll
        for (int kk = 0; kk < 32; ++kk) {
            const int slot = kk & 7;
            bf16x8 af0 = aw[slot][0], af1 = aw[slot][1];
            if (kk < 24) {
                aw[slot][0] = *(const bf16x8*)(a0p + ((kk + 8) << 5));
                aw[slot][1] = *(const bf16x8*)(a1p + ((kk + 8) << 5));
            }
            bf16x8 bfr[2];
            #pragma unroll
            for (int n = 0; n < 2; ++n)
                bfr[n] = *(const bf16x8*)&lB[(((((wc << 1) + n) << 5) + kk) << 6 | lane) << 3];
            acc[0][0] = __builtin_amdgcn_mfma_f32_16x16x32_bf16(af0, bfr[0], acc[0][0], 0, 0, 0);
            acc[0][1] = __builtin_amdgcn_mfma_f32_16x16x32_bf16(af0, bfr[1], acc[0][1], 0, 0, 0);
            acc[1][0] = __builtin_amdgcn_mfma_f32_16x16x32_bf16(af1, bfr[0], acc[1][0], 0, 0, 0);
            acc[1][1] = __builtin_amdgcn_mfma_f32_16x16x32_bf16(af1, bfr[1], acc[1][1], 0, 0, 0);
        }

        // Z exchange (prev step's post-gates sync protects lZ reuse),
        // skew (col + 4*row)&63 -> <=2-way conflicts (free, m136)
        {
            int q = lane >> 4, nl = lane & 15;
            #pragma unroll
            for (int m = 0; m < 2; ++m)
                #pragma unroll
                for (int n = 0; n < 2; ++n)
                    #pragma unroll
                    for (int r = 0; r < 4; ++r) {
                        int row = (wr << 5) + (m << 4) + (q << 2) + r;
                        int col = (wc << 5) + (n << 4) + nl;
                        lZ[(row << 6) + ((col + (row << 2)) & 63)] = acc[m][n][r];
                    }
        }
        __syncthreads();

        // gates + c/h update; h -> seq[t] (nontemporal: consumed cross-XCD only)
        #pragma unroll
        for (int i = 0; i < 4; ++i) {
            int idx = (i << 8) + tid;
            int row = idx >> 4, u = idx & 15;
            int rb4 = row << 2;
            float zi = lZ[(row << 6) + ((     u + rb4) & 63)] + bi[i];
            float zf = lZ[(row << 6) + ((16 + u + rb4) & 63)] + bfv[i];
            float zg = lZ[(row << 6) + ((32 + u + rb4) & 63)] + bg[i];
            float zo = lZ[(row << 6) + ((48 + u + rb4) & 63)] + bo[i];
            float cn = sigf(zf) * c_reg[i] + sigf(zi) * tanhf_(zg);
            c_reg[i] = cn;
            __builtin_nontemporal_store(f2bf(sigf(zo) * tanhf_(cn)),
                &seq[((size_t)t << 18) + (size_t)(r0 + row) * Hh + hb + u]);
        }

        if (t < Tt - 1) {
            __syncthreads();   // every wave's h-stores vmcnt-drained
            if (tid == 0) {
                unsigned xcd;
                asm volatile("s_getreg_b32 %0, hwreg(HW_REG_XCC_ID)" : "=s"(xcd));
                xcd &= 7;
                int old = __hip_atomic_fetch_add(&bar[xcd << 5], 1,
                                                 __ATOMIC_RELAXED, __HIP_MEMORY_SCOPE_AGENT);
                if ((old & 31) == 31) {
                    // last arriver on this physical XCD: ONE wbl2 (covers all
                    // 32 resident blocks' drained stores), then fan out
                    __hip_atomic_fetch_add(&bar[BAR_GFLAG], 1,
                                           __ATOMIC_RELEASE, __HIP_MEMORY_SCOPE_AGENT);
                    #pragma unroll
                    for (int g = 1; g < 8; ++g)
                        __hip_atomic_fetch_add(&bar[BAR_GFLAG + (g << 5)], 1,
                                               __ATOMIC_RELAXED, __HIP_MEMORY_SCOPE_AGENT);
                }
                if (id < 8) {
                    // master g=id: sole poller of gflag[id]; then broadcast to
                    // its logical group's 32 private lines (fire-and-forget)
                    int guard = 0;
                    while (__hip_atomic_fetch_add(&bar[BAR_GFLAG + (id << 5)], 0,
                                                  __ATOMIC_RELAXED, __HIP_MEMORY_SCOPE_AGENT)
                               < (t << 3) && ++guard < 300000)
                        __builtin_amdgcn_s_sleep(1);
                    #pragma unroll
                    for (int j = 0; j < 32; ++j)
                        __hip_atomic_fetch_add(&bar[BAR_BFLAG + ((id + (j << 3)) << 5)], 1,
                                               __ATOMIC_RELAXED, __HIP_MEMORY_SCOPE_AGENT);
                } else {
                    int guard = 0;
                    while (__hip_atomic_fetch_add(&bar[BAR_BFLAG + (id << 5)], 0,
                                                  __ATOMIC_RELAXED, __HIP_MEMORY_SCOPE_AGENT)
                               < t && ++guard < 300000)
                        __builtin_amdgcn_s_sleep(1);
                }
            }
            __syncthreads();
        }
    }
}

// ---------- batched emission, XCD-pinned, XOR-swizzled A staging ----------
__global__ __launch_bounds__(256) void emit(
    const ushort_t* __restrict__ seq,
    const ushort_t* __restrict__ Wsw,
    const float* __restrict__ bd,
    float* __restrict__ out)
{
    __shared__ __align__(16) ushort_t lA[2 * 8 * 64 * 8];
    __shared__ __align__(16) ushort_t lB[2 * 8 * 64 * 8];
    const int tid = threadIdx.x, w = tid >> 6, lane = tid & 63;
    const int id = blockIdx.x;
    const int rt = ((id >> 5) << 3) | (id & 7);
    const int ct = (id >> 3) & 3;
    const int r0 = rt << 7, f0 = ct << 7;
    const int wr = w >> 1, wc = w & 1;

    f32x4 acc[4][4];
    #pragma unroll
    for (int m = 0; m < 4; ++m)
        #pragma unroll
        for (int n = 0; n < 4; ++n) acc[m][n] = (f32x4){0.f, 0.f, 0.f, 0.f};

    for (int kc = 0; kc < Hh; kc += 64) {
        #pragma unroll
        for (int i = 0; i < 4; ++i) {
            int p = (i << 8) + tid;
            int row = p >> 3, kpp = p & 7;
            bf16x8 v = *(const bf16x8*)(seq + (size_t)(r0 + row) * Hh + kc + (kpp << 3));
            int kk = kpp >> 2, q = kpp & 3, msub = row >> 4, mm = row & 15;
            int pos = (q << 4) | (mm ^ (((kk << 2) + q) & 15));
            *(bf16x8*)&lA[((((kk << 3) + msub) << 6) + pos) << 3] = v;
        }
        #pragma unroll
        for (int i = 0; i < 4; ++i) {
            int d = (i << 8) + tid;
            int kk = d >> 9, csub = (d >> 6) & 7, ln = d & 63;
            int nt = (ct << 3) + csub;
            bf16x8 v = *(const bf16x8*)(Wsw + (((size_t)(nt * 32 + (kc >> 5) + kk)) << 9) + (ln << 3));
            *(bf16x8*)&lB[d << 3] = v;
        }
        __syncthreads();
        const int qq = lane >> 4, mm = lane & 15;
        #pragma unroll
        for (int kk = 0; kk < 2; ++kk) {
            const int pos = (qq << 4) | (mm ^ (((kk << 2) + qq) & 15));
            bf16x8 af[4], bfr[4];
            #pragma unroll
            for (int m = 0; m < 4; ++m)
                af[m] = *(const bf16x8*)&lA[((((kk << 3) + (wr << 2) + m) << 6) + pos) << 3];
            #pragma unroll
            for (int n = 0; n < 4; ++n)
                bfr[n] = *(const bf16x8*)&lB[((((kk << 3) + (wc << 2) + n) << 6) + lane) << 3];
            #pragma unroll
            for (int m = 0; m < 4; ++m)
                #pragma unroll
                for (int n = 0; n < 4; ++n)
                    acc[m][n] = __builtin_amdgcn_mfma_f32_16x16x32_bf16(
                        af[m], bfr[n], acc[m][n], 0, 0, 0);
        }
        __syncthreads();
    }

    int q = lane >> 4, nl = lane & 15;
    float bdv[4];
    #pragma unroll
    for (int n = 0; n < 4; ++n) bdv[n] = bd[f0 + (wc << 6) + (n << 4) + nl];
    #pragma unroll
    for (int m = 0; m < 4; ++m)
        #pragma unroll
        for (int r = 0; r < 4; ++r) {
            int grow = r0 + (wr << 6) + (m << 4) + (q << 2) + r;  // = t*256 + b
            int tt = grow >> 8, bb = grow & 255;
            float* op = out + ((size_t)((bb << 7) + tt) << 9);
            #pragma unroll
            for (int n = 0; n < 4; ++n)
                op[f0 + (wc << 6) + (n << 4) + nl] = acc[m][n][r] + bdv[n];
        }
}

// ---------- launch ----------
extern "C" void kernel_launch(void* const* d_in, const int* in_sizes, int n_in,
                              void* d_out, int out_size, void* d_ws, size_t ws_size,
                              hipStream_t stream)
{
    const float* x0 = (const float*)d_in[0];
    const float* h0 = (const float*)d_in[1];
    const float* c0 = (const float*)d_in[2];
    const float* W  = (const float*)d_in[3];
    const float* U  = (const float*)d_in[4];
    const float* b  = (const float*)d_in[5];
    const float* Wd = (const float*)d_in[6];
    const float* bd = (const float*)d_in[7];
    float* out = (float*)d_out;

    const size_t OFF_MCAT = 0;                  // 16,777,216
    const size_t OFF_MSUM = 16777216;           //  8,388,608
    const size_t OFF_WSW  = 25165824;           //  1,048,576
    const size_t OFF_A0   = 26214400;           //  1,048,576
    const size_t OFF_SEQ  = 27262976;           // 67,108,864
    const size_t OFF_BAR  = 94371840;           //     40,960
    const size_t WS_NEED  = 94412800;
    if (ws_size < WS_NEED) return;

    char* ws = (char*)d_ws;
    ushort_t* Mcat = (ushort_t*)(ws + OFF_MCAT);
    ushort_t* Msum = (ushort_t*)(ws + OFF_MSUM);
    ushort_t* Wsw  = (ushort_t*)(ws + OFF_WSW);
    ushort_t* A0   = (ushort_t*)(ws + OFF_A0);
    ushort_t* seq  = (ushort_t*)(ws + OFF_SEQ);
    int*      bar  = (int*)(ws + OFF_BAR);
    float* cws = out;   // c-state scratch: dead before emit overwrites out

    zero_bar<<<34, 256, 0, stream>>>(bar);
    mk_a0<<<2048, 256, 0, stream>>>(x0, h0, A0);
    swz<<<4096, 256, 0, stream>>>(W, U, Mcat, 2048, 4096, 1, 2048 * 4096);
    swz<<<2048, 256, 0, stream>>>(W, U, Msum, 1024, 4096, 0, 1024 * 4096);
    swz<<<512, 256, 0, stream>>>(Wd, nullptr, Wsw, 1024, 512, 2, 1024 * 512);

    lstm_step<<<256, 256, 0, stream>>>(A0, 2048, Mcat, c0, cws, seq, b);
    lstm_scan<<<256, 256, 0, stream>>>(seq, Msum, b, cws, bar);

    emit<<<1024, 256, 0, stream>>>(seq, Wsw, bd, out);
}

// Round 7
// 1101.129 us; speedup vs baseline: 1.9097x; 1.9097x over previous
//
#include <hip/hip_runtime.h>
#include <cstddef>
#include <cstdint>

typedef unsigned short ushort_t;
typedef __attribute__((ext_vector_type(8))) short bf16x8;
typedef __attribute__((ext_vector_type(4))) float f32x4;

#define Bb 256
#define Hh 1024
#define Ff 512
#define Tt 128

// ---------- helpers ----------
__device__ __forceinline__ ushort_t f2bf(float f) {
    unsigned int u = __float_as_uint(f);
    unsigned int r = (u + 0x7FFFu + ((u >> 16) & 1u)) >> 16;
    return (ushort_t)r;
}
__device__ __forceinline__ float sigf(float x)  { return 1.0f / (1.0f + __expf(-x)); }
__device__ __forceinline__ float tanhf_(float x){ return 2.0f / (1.0f + __expf(-2.0f * x)) - 1.0f; }

// ---------- weight swizzle: row-major fp32 [K][N] -> bf16 B-fragment blocks ----------
// 1KB blocks [ntile][kstep]; within: lane=(koff/8)*16+(n%16), j=koff%8.
// modes 0/1: gate-interleaved ntile = ugroup*4 + gate. mode 2 (Wd): plain.
__global__ void swz(const float* __restrict__ s0, const float* __restrict__ s1,
                    ushort_t* __restrict__ dst, int K, int N, int mode, int total)
{
    int KB = K >> 5;
    for (int idx = blockIdx.x * blockDim.x + threadIdx.x; idx < total;
         idx += gridDim.x * blockDim.x) {
        int blk   = idx >> 9;
        int lane  = (idx >> 3) & 63;
        int j     = idx & 7;
        int ntile = blk / KB;
        int kstep = blk - ntile * KB;
        int k = (kstep << 5) + ((lane >> 4) << 3) + j;
        int n;
        if (mode == 2) n = (ntile << 4) + (lane & 15);
        else           n = ((ntile & 3) << 10) + ((ntile >> 2) << 4) + (lane & 15);
        float v;
        if (mode == 0)      v = s0[(size_t)k * N + n] + s1[(size_t)k * N + n];
        else if (mode == 1) v = (k < 1024) ? s0[(size_t)k * N + n]
                                           : s1[(size_t)(k - 1024) * N + n];
        else                v = s0[(size_t)k * N + n];
        dst[idx] = f2bf(v);
    }
}

// ---------- A0 = [x0 | h0] as bf16, row-major [256][2048] ----------
__global__ void mk_a0(const float* __restrict__ x0, const float* __restrict__ h0,
                      ushort_t* __restrict__ a0)
{
    int idx = blockIdx.x * blockDim.x + threadIdx.x;
    if (idx >= Bb * 2048) return;
    int r = idx >> 11, k = idx & 2047;
    float v = (k < 1024) ? x0[r * 1024 + k] : h0[r * 1024 + k - 1024];
    a0[idx] = f2bf(v);
}

__global__ void zero_bar(int* bar) {
    int i = blockIdx.x * blockDim.x + threadIdx.x;
    if (i < 1024) bar[i] = 0;
}

// barrier word layout in bar[1024] (ints; 128B-spaced lines):
//   xcd arrival counter x : bar[x*32]   (x=0..7, physical XCD, +32/step)
//   root                  : bar[256]    (+8/step)
//   replica flag r        : bar[320+r*32] (r=0..7, +1/step)
#define BAR_ROOT 256
#define BAR_FLAG 320

// ---------- step 0 (K=2048, Mcat streamed): round-2 kernel, proven ----------
__global__ __launch_bounds__(256) void lstm_step(
    const ushort_t* __restrict__ Ap, int K,
    const ushort_t* __restrict__ Bw,
    const float* cin, float* cout,
    ushort_t* __restrict__ seqt,
    const float* __restrict__ bias)
{
    __shared__ __align__(16) ushort_t lA[32 * 512];
    __shared__ __align__(16) ushort_t lB[32 * 512];

    const int tid = threadIdx.x, w = tid >> 6, lane = tid & 63;
    const int id = blockIdx.x;
    const int ntg = ((id & 7) << 3) | (id >> 5);
    const int bt  = (id >> 3) & 3;
    const int r0 = bt << 6, hb = ntg << 4;
    const int wr = w >> 1, wc = w & 1;
    const int KB = K >> 5;

    f32x4 acc[2][2];
    #pragma unroll
    for (int m = 0; m < 2; ++m)
        #pragma unroll
        for (int n = 0; n < 2; ++n) acc[m][n] = (f32x4){0.f, 0.f, 0.f, 0.f};

    const int kp = tid & 31;
    const int q_a = kp & 3, kk_a = kp >> 2;

    for (int kc = 0; kc < K; kc += 256) {
        bf16x8 va[8];
        #pragma unroll
        for (int i = 0; i < 8; ++i) {
            int row = (i << 3) + (tid >> 5);
            va[i] = *(const bf16x8*)(Ap + (size_t)(r0 + row) * K + kc + (kp << 3));
        }
        bf16x8 vb[8];
        #pragma unroll
        for (int i = 0; i < 8; ++i)
            vb[i] = *(const bf16x8*)(Bw +
                ((((size_t)((ntg << 2) + w)) * KB + (kc >> 5) + i) << 9) + (lane << 3));
        #pragma unroll
        for (int i = 0; i < 8; ++i) {
            int row = (i << 3) + (tid >> 5);
            int msub = row >> 4, mm = row & 15;
            int pos = (q_a << 4) | (mm ^ (((kk_a << 2) + q_a) & 15));
            *(bf16x8*)&lA[((((kk_a << 2) + msub) << 6) + pos) << 3] = va[i];
        }
        #pragma unroll
        for (int i = 0; i < 8; ++i)
            *(bf16x8*)&lB[(((i << 2) + w) << 9) + (lane << 3)] = vb[i];
        __syncthreads();

        #pragma unroll
        for (int kk = 0; kk < 8; ++kk) {
            const int qq = lane >> 4, mm = lane & 15;
            const int pos = (qq << 4) | (mm ^ (((kk << 2) + qq) & 15));
            bf16x8 af[2], bfr[2];
            #pragma unroll
            for (int m = 0; m < 2; ++m)
                af[m] = *(const bf16x8*)&lA[((((kk << 2) + (wr << 1) + m) << 6) + pos) << 3];
            #pragma unroll
            for (int n = 0; n < 2; ++n)
                bfr[n] = *(const bf16x8*)&lB[((((kk << 2) + (wc << 1) + n) << 6) + lane) << 3];
            #pragma unroll
            for (int m = 0; m < 2; ++m)
                #pragma unroll
                for (int n = 0; n < 2; ++n)
                    acc[m][n] = __builtin_amdgcn_mfma_f32_16x16x32_bf16(
                        af[m], bfr[n], acc[m][n], 0, 0, 0);
        }
        __syncthreads();
    }

    float* lZ = (float*)lA;
    {
        int q = lane >> 4, nl = lane & 15;
        #pragma unroll
        for (int m = 0; m < 2; ++m)
            #pragma unroll
            for (int n = 0; n < 2; ++n)
                #pragma unroll
                for (int r = 0; r < 4; ++r)
                    lZ[((wr << 5) + (m << 4) + (q << 2) + r) * 68 +
                       (wc << 5) + (n << 4) + nl] = acc[m][n][r];
    }
    __syncthreads();

    #pragma unroll
    for (int i = 0; i < 4; ++i) {
        int idx = (i << 8) + tid;
        int row = idx >> 4, u = idx & 15;
        float zi = lZ[row * 68 +      u] + bias[       hb + u];
        float zf = lZ[row * 68 + 16 + u] + bias[1024 + hb + u];
        float zg = lZ[row * 68 + 32 + u] + bias[2048 + hb + u];
        float zo = lZ[row * 68 + 48 + u] + bias[3072 + hb + u];
        size_t cidx = (size_t)(r0 + row) * Hh + hb + u;
        float cp = cin[cidx];
        float cn = sigf(zf) * cp + sigf(zi) * tanhf_(zg);
        cout[cidx] = cn;
        seqt[cidx] = f2bf(sigf(zo) * tanhf_(cn));
    }
}

// ---------- persistent scan, steps 1..127 ----------
// Round-5 compute structure (known-good 1174us) with ONE change: h published
// via 8B atomic swaps (RMW -> coherent point, visible device-wide) so the
// barrier needs NO release/wbl2 anywhere — fully relaxed tree. Round-6's NT
// stores (HBM write-through) and master-relay hop are reverted.
__global__ __launch_bounds__(256) void lstm_scan(
    ushort_t* __restrict__ seq,
    const ushort_t* __restrict__ Msum,
    const float* __restrict__ bias,
    const float* __restrict__ cin,
    int* __restrict__ bar)
{
    __shared__ __align__(16) ushort_t lB[65536];    // 128 KB resident B
    __shared__ __align__(16) ushort_t lA[2][8192];  // 2 x 16 KB A chunks

    const int tid = threadIdx.x, w = tid >> 6, lane = tid & 63;
    const int id = blockIdx.x;
    const int ntg = ((id & 7) << 3) | (id >> 5);
    const int bt  = (id >> 3) & 3;
    const int r0 = bt << 6, hb = ntg << 4;
    const int wr = w >> 1, wc = w & 1;

    // resident B: contiguous 128 KB slice (ntile-major global layout)
    {
        const ushort_t* src = Msum + ((size_t)ntg << 16);
        #pragma unroll
        for (int i = 0; i < 32; ++i)
            *(bf16x8*)&lB[((i << 8) + tid) << 3] =
                *(const bf16x8*)(src + (((i << 8) + tid) << 3));
    }

    // c-state + bias in registers; thread owns 4 consecutive cells:
    // row = tid>>2 (0..63), u = (tid&3)*4 + j  -> one 8B pack per step
    const int grow = tid >> 2, guq = (tid & 3) << 2;
    float c_reg[4], bi[4], bfv[4], bg[4], bo[4];
    #pragma unroll
    for (int j = 0; j < 4; ++j) {
        int u = guq + j;
        c_reg[j] = cin[(size_t)(r0 + grow) * Hh + hb + u];
        bi[j]  = bias[       hb + u];
        bfv[j] = bias[1024 + hb + u];
        bg[j]  = bias[2048 + hb + u];
        bo[j]  = bias[3072 + hb + u];
    }

    float* lZ = (float*)lA;
    // A staging geometry: piece p = i*256+tid (i=0..3), row = p>>4, kp = p&15
    const int kp   = tid & 15;
    const int q_a  = kp & 3, kk_a = kp >> 2;

    for (int t = 1; t < Tt; ++t) {
        const ushort_t* Ap = seq + ((size_t)(t - 1) << 18);

        f32x4 acc[2][2];
        #pragma unroll
        for (int m = 0; m < 2; ++m)
            #pragma unroll
            for (int n = 0; n < 2; ++n) acc[m][n] = (f32x4){0.f, 0.f, 0.f, 0.f};

        bf16x8 rA[2][4];
        // prologue: chunk0 -> rA[0] -> lA[0]; chunk1 -> rA[1]
        #pragma unroll
        for (int i = 0; i < 4; ++i) {
            int row = (i << 4) + (tid >> 4);
            rA[0][i] = *(const bf16x8*)(Ap + (size_t)(r0 + row) * Hh + (kp << 3));
        }
        #pragma unroll
        for (int i = 0; i < 4; ++i) {
            int row = (i << 4) + (tid >> 4);
            int msub = row >> 4, mm = row & 15;
            int pos = (q_a << 4) | (mm ^ (((kk_a << 2) + q_a) & 15));
            *(bf16x8*)&lA[0][((((kk_a << 2) + msub) << 6) + pos) << 3] = rA[0][i];
        }
        #pragma unroll
        for (int i = 0; i < 4; ++i) {
            int row = (i << 4) + (tid >> 4);
            rA[1][i] = *(const bf16x8*)(Ap + (size_t)(r0 + row) * Hh + 128 + (kp << 3));
        }
        __syncthreads();

        for (int kc = 0; kc < 8; ++kc) {
            if (kc < 7) {   // stage chunk kc+1 (regs loaded >=1 iter ago)
                int s = (kc + 1) & 1;
                #pragma unroll
                for (int i = 0; i < 4; ++i) {
                    int row = (i << 4) + (tid >> 4);
                    int msub = row >> 4, mm = row & 15;
                    int pos = (q_a << 4) | (mm ^ (((kk_a << 2) + q_a) & 15));
                    *(bf16x8*)&lA[s][((((kk_a << 2) + msub) << 6) + pos) << 3] = rA[s][i];
                }
            }
            if (kc < 6) {   // issue loads for chunk kc+2
                int s = kc & 1, k0 = (kc + 2) << 7;
                #pragma unroll
                for (int i = 0; i < 4; ++i) {
                    int row = (i << 4) + (tid >> 4);
                    rA[s][i] = *(const bf16x8*)(Ap + (size_t)(r0 + row) * Hh + k0 + (kp << 3));
                }
            }
            const ushort_t* lAc = lA[kc & 1];
            const int qq = lane >> 4, mm = lane & 15;
            #pragma unroll
            for (int kk = 0; kk < 4; ++kk) {
                int ks = (kc << 2) + kk;
                const int pos = (qq << 4) | (mm ^ (((kk << 2) + qq) & 15));
                bf16x8 af[2], bfr[2];
                #pragma unroll
                for (int m = 0; m < 2; ++m)
                    af[m] = *(const bf16x8*)&lAc[((((kk << 2) + (wr << 1) + m) << 6) + pos) << 3];
                #pragma unroll
                for (int n = 0; n < 2; ++n)
                    bfr[n] = *(const bf16x8*)&lB[(((((wc << 1) + n) << 5) + ks) << 6 | lane) << 3];
                #pragma unroll
                for (int m = 0; m < 2; ++m)
                    #pragma unroll
                    for (int n = 0; n < 2; ++n)
                        acc[m][n] = __builtin_amdgcn_mfma_f32_16x16x32_bf16(
                            af[m], bfr[n], acc[m][n], 0, 0, 0);
            }
            __syncthreads();
        }

        // Z exchange into lA region, skew (col + 4*row)&63 -> <=2-way conflicts
        {
            int q = lane >> 4, nl = lane & 15;
            #pragma unroll
            for (int m = 0; m < 2; ++m)
                #pragma unroll
                for (int n = 0; n < 2; ++n)
                    #pragma unroll
                    for (int r = 0; r < 4; ++r) {
                        int row = (wr << 5) + (m << 4) + (q << 2) + r;
                        int col = (wc << 5) + (n << 4) + nl;
                        lZ[(row << 6) + ((col + (row << 2)) & 63)] = acc[m][n][r];
                    }
        }
        __syncthreads();

        // gates + c/h update; h published as ONE 8B atomic swap per thread
        // (RMW executes at coherent point -> cross-XCD visible, no wbl2 needed)
        {
            const int rb4 = grow << 2;
            unsigned long long pk = 0;
            #pragma unroll
            for (int j = 0; j < 4; ++j) {
                int u = guq + j;
                float zi = lZ[(grow << 6) + ((     u + rb4) & 63)] + bi[j];
                float zf = lZ[(grow << 6) + ((16 + u + rb4) & 63)] + bfv[j];
                float zg = lZ[(grow << 6) + ((32 + u + rb4) & 63)] + bg[j];
                float zo = lZ[(grow << 6) + ((48 + u + rb4) & 63)] + bo[j];
                float cn = sigf(zf) * c_reg[j] + sigf(zi) * tanhf_(zg);
                c_reg[j] = cn;
                pk |= (unsigned long long)f2bf(sigf(zo) * tanhf_(cn)) << (j << 4);
            }
            __hip_atomic_exchange(
                (unsigned long long*)&seq[((size_t)t << 18) +
                                          (size_t)(r0 + grow) * Hh + hb + guq],
                pk, __ATOMIC_RELAXED, __HIP_MEMORY_SCOPE_AGENT);
        }

        if (t < Tt - 1) {
            __syncthreads();   // drains vmcnt incl. swaps -> acked at coherent pt
            if (tid == 0) {
                unsigned xcd;
                asm volatile("s_getreg_b32 %0, hwreg(HW_REG_XCC_ID)" : "=s"(xcd));
                xcd &= 7;
                // arrival: RELAXED (zero cache maintenance in whole barrier)
                int old = __hip_atomic_fetch_add(&bar[xcd << 5], 1,
                                                 __ATOMIC_RELAXED, __HIP_MEMORY_SCOPE_AGENT);
                if ((old & 31) == 31) {
                    int rv = __hip_atomic_fetch_add(&bar[BAR_ROOT], 1,
                                                    __ATOMIC_RELAXED, __HIP_MEMORY_SCOPE_AGENT);
                    if ((rv & 7) == 7) {   // 8th XCD this step: open the gates
                        #pragma unroll
                        for (int r = 0; r < 8; ++r)
                            __hip_atomic_fetch_add(&bar[BAR_FLAG + (r << 5)], 1,
                                                   __ATOMIC_RELAXED, __HIP_MEMORY_SCOPE_AGENT);
                    }
                }
                // poll replica via RMW (coherent point; relaxed plain loads
                // see stale L2 cross-XCD — round-3 evidence)
                int guard = 0;
                while (__hip_atomic_fetch_add(&bar[BAR_FLAG + ((id & 7) << 5)], 0,
                                              __ATOMIC_RELAXED, __HIP_MEMORY_SCOPE_AGENT) < t
                       && ++guard < 200000)
                    __builtin_amdgcn_s_sleep(2);
            }
            __syncthreads();
        }
    }
}

// ---------- batched emission, XCD-pinned, XOR-swizzled A staging ----------
__global__ __launch_bounds__(256) void emit(
    const ushort_t* __restrict__ seq,
    const ushort_t* __restrict__ Wsw,
    const float* __restrict__ bd,
    float* __restrict__ out)
{
    __shared__ __align__(16) ushort_t lA[2 * 8 * 64 * 8];
    __shared__ __align__(16) ushort_t lB[2 * 8 * 64 * 8];
    const int tid = threadIdx.x, w = tid >> 6, lane = tid & 63;
    const int id = blockIdx.x;
    const int rt = ((id >> 5) << 3) | (id & 7);
    const int ct = (id >> 3) & 3;
    const int r0 = rt << 7, f0 = ct << 7;
    const int wr = w >> 1, wc = w & 1;

    f32x4 acc[4][4];
    #pragma unroll
    for (int m = 0; m < 4; ++m)
        #pragma unroll
        for (int n = 0; n < 4; ++n) acc[m][n] = (f32x4){0.f, 0.f, 0.f, 0.f};

    for (int kc = 0; kc < Hh; kc += 64) {
        #pragma unroll
        for (int i = 0; i < 4; ++i) {
            int p = (i << 8) + tid;
            int row = p >> 3, kpp = p & 7;
            bf16x8 v = *(const bf16x8*)(seq + (size_t)(r0 + row) * Hh + kc + (kpp << 3));
            int kk = kpp >> 2, q = kpp & 3, msub = row >> 4, mm = row & 15;
            int pos = (q << 4) | (mm ^ (((kk << 2) + q) & 15));
            *(bf16x8*)&lA[((((kk << 3) + msub) << 6) + pos) << 3] = v;
        }
        #pragma unroll
        for (int i = 0; i < 4; ++i) {
            int d = (i << 8) + tid;
            int kk = d >> 9, csub = (d >> 6) & 7, ln = d & 63;
            int nt = (ct << 3) + csub;
            bf16x8 v = *(const bf16x8*)(Wsw + (((size_t)(nt * 32 + (kc >> 5) + kk)) << 9) + (ln << 3));
            *(bf16x8*)&lB[d << 3] = v;
        }
        __syncthreads();
        const int qq = lane >> 4, mm = lane & 15;
        #pragma unroll
        for (int kk = 0; kk < 2; ++kk) {
            const int pos = (qq << 4) | (mm ^ (((kk << 2) + qq) & 15));
            bf16x8 af[4], bfr[4];
            #pragma unroll
            for (int m = 0; m < 4; ++m)
                af[m] = *(const bf16x8*)&lA[((((kk << 3) + (wr << 2) + m) << 6) + pos) << 3];
            #pragma unroll
            for (int n = 0; n < 4; ++n)
                bfr[n] = *(const bf16x8*)&lB[((((kk << 3) + (wc << 2) + n) << 6) + lane) << 3];
            #pragma unroll
            for (int m = 0; m < 4; ++m)
                #pragma unroll
                for (int n = 0; n < 4; ++n)
                    acc[m][n] = __builtin_amdgcn_mfma_f32_16x16x32_bf16(
                        af[m], bfr[n], acc[m][n], 0, 0, 0);
        }
        __syncthreads();
    }

    int q = lane >> 4, nl = lane & 15;
    float bdv[4];
    #pragma unroll
    for (int n = 0; n < 4; ++n) bdv[n] = bd[f0 + (wc << 6) + (n << 4) + nl];
    #pragma unroll
    for (int m = 0; m < 4; ++m)
        #pragma unroll
        for (int r = 0; r < 4; ++r) {
            int grow2 = r0 + (wr << 6) + (m << 4) + (q << 2) + r;  // = t*256 + b
            int tt = grow2 >> 8, bb = grow2 & 255;
            float* op = out + ((size_t)((bb << 7) + tt) << 9);
            #pragma unroll
            for (int n = 0; n < 4; ++n)
                op[f0 + (wc << 6) + (n << 4) + nl] = acc[m][n][r] + bdv[n];
        }
}

// ---------- launch ----------
extern "C" void kernel_launch(void* const* d_in, const int* in_sizes, int n_in,
                              void* d_out, int out_size, void* d_ws, size_t ws_size,
                              hipStream_t stream)
{
    const float* x0 = (const float*)d_in[0];
    const float* h0 = (const float*)d_in[1];
    const float* c0 = (const float*)d_in[2];
    const float* W  = (const float*)d_in[3];
    const float* U  = (const float*)d_in[4];
    const float* b  = (const float*)d_in[5];
    const float* Wd = (const float*)d_in[6];
    const float* bd = (const float*)d_in[7];
    float* out = (float*)d_out;

    const size_t OFF_MCAT = 0;                  // 16,777,216
    const size_t OFF_MSUM = 16777216;           //  8,388,608
    const size_t OFF_WSW  = 25165824;           //  1,048,576
    const size_t OFF_A0   = 26214400;           //  1,048,576
    const size_t OFF_SEQ  = 27262976;           // 67,108,864
    const size_t OFF_BAR  = 94371840;           //      4,096
    const size_t WS_NEED  = 94375936;
    if (ws_size < WS_NEED) return;

    char* ws = (char*)d_ws;
    ushort_t* Mcat = (ushort_t*)(ws + OFF_MCAT);
    ushort_t* Msum = (ushort_t*)(ws + OFF_MSUM);
    ushort_t* Wsw  = (ushort_t*)(ws + OFF_WSW);
    ushort_t* A0   = (ushort_t*)(ws + OFF_A0);
    ushort_t* seq  = (ushort_t*)(ws + OFF_SEQ);
    int*      bar  = (int*)(ws + OFF_BAR);
    float* cws = out;   // c-state scratch: dead before emit overwrites out

    zero_bar<<<4, 256, 0, stream>>>(bar);
    mk_a0<<<2048, 256, 0, stream>>>(x0, h0, A0);
    swz<<<4096, 256, 0, stream>>>(W, U, Mcat, 2048, 4096, 1, 2048 * 4096);
    swz<<<2048, 256, 0, stream>>>(W, U, Msum, 1024, 4096, 0, 1024 * 4096);
    swz<<<512, 256, 0, stream>>>(Wd, nullptr, Wsw, 1024, 512, 2, 1024 * 512);

    lstm_step<<<256, 256, 0, stream>>>(A0, 2048, Mcat, c0, cws, seq, b);
    lstm_scan<<<256, 256, 0, stream>>>(seq, Msum, b, cws, bar);

    emit<<<1024, 256, 0, stream>>>(seq, Wsw, bd, out);
}